// Round 5
// baseline (90.579 us; speedup 1.0000x reference)
//
#include <hip/hip_runtime.h>
#include <math.h>

#define B_ 4096
#define T_ 64
#define E_ 256
#define H_ 64
#define THREADS 512

typedef __attribute__((ext_vector_type(8))) short bf16x8;
typedef __attribute__((ext_vector_type(4))) float f32x4;

__device__ __forceinline__ unsigned short f2bf_u(float x) {
    unsigned u = __float_as_uint(x);
    return (unsigned short)((u + 0x7FFFu + ((u >> 16) & 1u)) >> 16);
}
__device__ __forceinline__ short f2bf(float x) { return (short)f2bf_u(x); }
__device__ __forceinline__ float sigm(float x) { return 1.0f / (1.0f + __expf(-x)); }
__device__ __forceinline__ float tanh_(float x) { return 1.0f - 2.0f / (1.0f + __expf(2.0f * x)); }

// ---------------------------------------------------------------------------
// Prep (identical layout to R4, verified):
//  wih_frag[((vv*2+tl)*8 + kc)*512 + lane*8 + jj]:
//    gate g = tl*128 + (lane&1)*64 + vv*8 + ((lane&15)>>1)
//    k      = kc*32 + (lane>>4)*8 + jj        (vv = virtual wave 0..7)
//  whh_g: bf16 [g][k] row-major;  bias_f = b_ih + b_hh
// ---------------------------------------------------------------------------
__global__ void prep_kernel(const float* __restrict__ W_ih,
                            const float* __restrict__ W_hh,
                            const float* __restrict__ b_ih,
                            const float* __restrict__ b_hh,
                            short* __restrict__ wih_frag,
                            short* __restrict__ whh_g,
                            float* __restrict__ bias_f) {
    int tid = blockIdx.x * blockDim.x + threadIdx.x;
    int stride = gridDim.x * blockDim.x;
    for (int i = tid; i < 65536; i += stride) {
        int jj = i & 7;
        int l  = (i >> 3) & 63;
        int kc = (i >> 9) & 7;
        int tl = (i >> 12) & 1;
        int vv = i >> 13;
        int uu = (l & 15) >> 1, pp = l & 1;
        int g = tl * 128 + pp * 64 + vv * 8 + uu;
        int k = kc * 32 + (l >> 4) * 8 + jj;
        wih_frag[i] = f2bf(W_ih[g * E_ + k]);
    }
    for (int i = tid; i < 256 * 64; i += stride) whh_g[i] = f2bf(W_hh[i]);
    for (int i = tid; i < 256; i += stride) bias_f[i] = b_ih[i] + b_hh[i];
}

// ---------------------------------------------------------------------------
// Fused pipelined MFMA LSTM. grid 256, 512 threads = 8 waves:
//  waves 0-3: compute, each owns 4 gate tiles (2 virtual waves x (i/f , g/o)).
//             W_ih (128 VGPR) + W_hh (32 VGPR) register-resident.
//  waves 4-7: stage emb(t+2) f32->bf16 into fragment-ordered dbuf LDS.
// LDS fragment layout: chunk (kc, lane) at byte kc*1024 + 16*lane holds
//   A[m=lane&15][k=kc*32+(lane>>4)*8+jj] -> all reads/writes are contiguous
//   1024B blocks = zero bank conflicts by construction.
// Per step: [R] h-MFMA(4x2) + in-register gates + packed h write,
//           [P] preG(t+1) = bias + emb(t+1)*W_ih (8 ds_read + 32 MFMA),
// one barrier per step. P is unguarded (reads stale buf at t=63, unused).
// ---------------------------------------------------------------------------
__global__ __launch_bounds__(THREADS, 2)
void lstm_pipe4(const int* __restrict__ x,
                const float* __restrict__ emb,
                const short* __restrict__ wih_frag,
                const short* __restrict__ whh_g,
                const float* __restrict__ bias_f,
                float* __restrict__ out) {
    __shared__ __align__(16) short s_ef[2 * 4096];  // 16 KB: [buf][kc][lane]
    __shared__ __align__(16) short s_hf[2 * 1024];  // 4 KB:  [buf][kc][lane]
    __shared__ int s_idx[1024];                     // [t][m]

    const int tid  = threadIdx.x;
    const int lane = tid & 63;
    const int wave = tid >> 6;
    const int r0   = blockIdx.x * 16;

    for (int i = tid; i < 1024; i += THREADS)
        s_idx[i] = x[(r0 + (i & 15)) * T_ + (i >> 4)];
    for (int i = tid; i < 1024; i += THREADS)
        ((int*)s_hf)[i] = 0;

    const int p  = lane & 1;
    const int c4 = lane >> 4;
    const int u  = (lane & 15) >> 1;
    const float scl2 = p ? 1.0f : 2.0f;
    const float offB = p ? 0.0f : -1.0f;

    // stage mapping (waves 4..7): 2 k-chunks per wave, lane == fragment slot
    const int sm   = lane & 15;
    const int skc0 = (wave - 4) * 2;
    const int sk0  = skc0 * 32 + c4 * 8;

    bf16x8 wA[2][8], wB[2][8], qA[2][2], qB[2][2];
    float bA[2] = {0.f, 0.f}, bB[2] = {0.f, 0.f};
    int hw_off[2] = {0, 0};

    if (wave < 4) {
        #pragma unroll
        for (int t2 = 0; t2 < 2; ++t2) {
            const int vv = wave * 2 + t2;
            const short* wp = wih_frag + vv * 8192 + lane * 8;
            #pragma unroll
            for (int kc = 0; kc < 8; ++kc) {
                wA[t2][kc] = *(const bf16x8*)(wp + kc * 512);
                wB[t2][kc] = *(const bf16x8*)(wp + 4096 + kc * 512);
            }
            const int gA = p * 64 + vv * 8 + u;
            const short* qp = whh_g + gA * 64 + c4 * 8;
            qA[t2][0] = *(const bf16x8*)(qp);
            qA[t2][1] = *(const bf16x8*)(qp + 32);
            qB[t2][0] = *(const bf16x8*)(qp + 8192);       // (gA+128)*64
            qB[t2][1] = *(const bf16x8*)(qp + 8192 + 32);
            bA[t2] = bias_f[gA];
            bB[t2] = bias_f[gA + 128];
            const int m0 = c4 * 4 + p * 2;
            const int up = u & 1;
            hw_off[t2] = (vv >> 2) * 1024 + 256 * (vv & 3)
                       + (up ? 16 * (m0 + 1) + 2 * (u - 1) : 16 * m0 + 2 * u);
        }
    }

    auto stage = [&](int tt, int buf) {
        int tok = s_idx[tt * 16 + sm];
        const float* pr = emb + (size_t)tok * E_ + sk0;
        float4 f0 = *(const float4*)pr;
        float4 f1 = *(const float4*)(pr + 4);
        float4 f2 = *(const float4*)(pr + 32);
        float4 f3 = *(const float4*)(pr + 36);
        bf16x8 wlo, whi;
        wlo[0] = f2bf(f0.x); wlo[1] = f2bf(f0.y); wlo[2] = f2bf(f0.z); wlo[3] = f2bf(f0.w);
        wlo[4] = f2bf(f1.x); wlo[5] = f2bf(f1.y); wlo[6] = f2bf(f1.z); wlo[7] = f2bf(f1.w);
        whi[0] = f2bf(f2.x); whi[1] = f2bf(f2.y); whi[2] = f2bf(f2.z); whi[3] = f2bf(f2.w);
        whi[4] = f2bf(f3.x); whi[5] = f2bf(f3.y); whi[6] = f2bf(f3.z); whi[7] = f2bf(f3.w);
        char* db = (char*)s_ef + buf * 8192 + lane * 16;
        *(bf16x8*)(db + skc0 * 1024)        = wlo;
        *(bf16x8*)(db + skc0 * 1024 + 1024) = whi;
    };

    __syncthreads();   // s_idx, h=0 visible

    if (wave >= 4) { stage(0, 0); stage(1, 1); }
    __syncthreads();   // emb(0), emb(1) staged

    f32x4 pA[2], pB[2];
    if (wave < 4) {
        // preG(0) = bias + emb(0)*Wih
        const char* eb = (const char*)s_ef + lane * 16;
        #pragma unroll
        for (int t2 = 0; t2 < 2; ++t2) {
            pA[t2] = (f32x4){bA[t2], bA[t2], bA[t2], bA[t2]};
            pB[t2] = (f32x4){bB[t2], bB[t2], bB[t2], bB[t2]};
        }
        #pragma unroll
        for (int kc = 0; kc < 8; ++kc) {
            bf16x8 av = *(const bf16x8*)(eb + kc * 1024);
            #pragma unroll
            for (int t2 = 0; t2 < 2; ++t2) {
                pA[t2] = __builtin_amdgcn_mfma_f32_16x16x32_bf16(av, wA[t2][kc], pA[t2], 0, 0, 0);
                pB[t2] = __builtin_amdgcn_mfma_f32_16x16x32_bf16(av, wB[t2][kc], pB[t2], 0, 0, 0);
            }
        }
    }
    __syncthreads();   // protects ebuf0 from t=0 staging

    float c0[2] = {0.f, 0.f}, c1[2] = {0.f, 0.f};
    float h0[2] = {0.f, 0.f}, h1[2] = {0.f, 0.f};

    for (int t = 0; t < T_; ++t) {
        if (wave < 4) {
            // ---- phase R: G(t) = preG + h(t-1)*Whh ; gates ----
            const char* hb = (const char*)s_hf + (t & 1) * 2048 + lane * 16;
            bf16x8 hv0 = *(const bf16x8*)(hb);
            bf16x8 hv1 = *(const bf16x8*)(hb + 1024);
            #pragma unroll
            for (int t2 = 0; t2 < 2; ++t2) {
                pA[t2] = __builtin_amdgcn_mfma_f32_16x16x32_bf16(hv0, qA[t2][0], pA[t2], 0, 0, 0);
                pA[t2] = __builtin_amdgcn_mfma_f32_16x16x32_bf16(hv1, qA[t2][1], pA[t2], 0, 0, 0);
                pB[t2] = __builtin_amdgcn_mfma_f32_16x16x32_bf16(hv0, qB[t2][0], pB[t2], 0, 0, 0);
                pB[t2] = __builtin_amdgcn_mfma_f32_16x16x32_bf16(hv1, qB[t2][1], pB[t2], 0, 0, 0);
            }
            #pragma unroll
            for (int t2 = 0; t2 < 2; ++t2) {
                float sA[4], Bv[4];
                #pragma unroll
                for (int q = 0; q < 4; ++q) {
                    sA[q] = sigm(pA[t2][q]);                  // sigm(i) | sigm(f)
                    Bv[q] = sigm(scl2 * pB[t2][q]) * scl2 + offB;  // tanh(g) | sigm(o)
                }
                float s1 = p ? sA[0] : sA[2] * Bv[2];
                float r1 = __shfl_xor(s1, 1);
                float s2 = p ? sA[1] : sA[3] * Bv[3];
                float r2 = __shfl_xor(s2, 1);
                float r3 = __shfl_xor(Bv[0], 1);
                float r4 = __shfl_xor(Bv[1], 1);
                float fc0 = p ? sA[2] : r1;
                float ic0 = p ? r1 : sA[0] * Bv[0];
                float oc0 = p ? Bv[2] : r3;
                float fc1 = p ? sA[3] : r2;
                float ic1 = p ? r2 : sA[1] * Bv[1];
                float oc1 = p ? Bv[3] : r4;
                c0[t2] = fc0 * c0[t2] + ic0;
                c1[t2] = fc1 * c1[t2] + ic1;
                h0[t2] = oc0 * tanh_(c0[t2]);
                h1[t2] = oc1 * tanh_(c1[t2]);
                // packed b32 h-write (pair exchange over u-parity, lane^2)
                unsigned int sh0 = f2bf_u(h0[t2]), sh1 = f2bf_u(h1[t2]);
                unsigned int snd = (u & 1) ? sh0 : sh1;
                unsigned int rcv = (unsigned int)__shfl_xor((int)snd, 2);
                unsigned int wv = (u & 1) ? (rcv | (sh1 << 16)) : (sh0 | (rcv << 16));
                *(unsigned int*)((char*)s_hf + ((t + 1) & 1) * 2048 + hw_off[t2]) = wv;
            }
            // ---- phase P: preG(t+1) = bias + emb(t+1)*Wih (unguarded) ----
            const char* eb = (const char*)s_ef + ((t + 1) & 1) * 8192 + lane * 16;
            #pragma unroll
            for (int t2 = 0; t2 < 2; ++t2) {
                pA[t2] = (f32x4){bA[t2], bA[t2], bA[t2], bA[t2]};
                pB[t2] = (f32x4){bB[t2], bB[t2], bB[t2], bB[t2]};
            }
            #pragma unroll
            for (int kc = 0; kc < 8; ++kc) {
                bf16x8 av = *(const bf16x8*)(eb + kc * 1024);
                #pragma unroll
                for (int t2 = 0; t2 < 2; ++t2) {
                    pA[t2] = __builtin_amdgcn_mfma_f32_16x16x32_bf16(av, wA[t2][kc], pA[t2], 0, 0, 0);
                    pB[t2] = __builtin_amdgcn_mfma_f32_16x16x32_bf16(av, wB[t2][kc], pB[t2], 0, 0, 0);
                }
            }
        } else {
            int tt = (t + 2 < T_) ? t + 2 : T_ - 1;   // clamp: redundant re-stage, safe
            stage(tt, t & 1);
        }
        __syncthreads();
    }

    if (wave < 4) {
        const int m0 = c4 * 4 + p * 2;
        #pragma unroll
        for (int t2 = 0; t2 < 2; ++t2) {
            const int j = (wave * 2 + t2) * 8 + u;
            out[(r0 + m0) * H_ + j]     = h0[t2];
            out[(r0 + m0 + 1) * H_ + j] = h1[t2];
        }
    }
}

// ---------------------------------------------------------------------------
extern "C" void kernel_launch(void* const* d_in, const int* in_sizes, int n_in,
                              void* d_out, int out_size, void* d_ws, size_t ws_size,
                              hipStream_t stream) {
    const int*   x         = (const int*)d_in[0];
    const float* emb_table = (const float*)d_in[1];
    const float* W_ih      = (const float*)d_in[2];
    const float* W_hh      = (const float*)d_in[3];
    const float* b_ih      = (const float*)d_in[4];
    const float* b_hh      = (const float*)d_in[5];
    float*       out       = (float*)d_out;

    short* wih_frag = (short*)d_ws;               // 65536 shorts (128 KB)
    short* whh_g    = wih_frag + 65536;           // 16384 shorts (32 KB)
    float* bias_f   = (float*)(whh_g + 16384);    // 256 floats (1 KB)

    prep_kernel<<<64, 256, 0, stream>>>(W_ih, W_hh, b_ih, b_hh,
                                        wih_frag, whh_g, bias_f);
    lstm_pipe4<<<B_ / 16, THREADS, 0, stream>>>(x, emb_table,
                                                wih_frag, whh_g, bias_f, out);
}